// Round 1
// baseline (99.581 us; speedup 1.0000x reference)
//
#include <hip/hip_runtime.h>
#include <hip/hip_bf16.h>

typedef __bf16 bf16x8 __attribute__((ext_vector_type(8)));
typedef __bf16 bf16x4 __attribute__((ext_vector_type(4)));
typedef float  f32x4  __attribute__((ext_vector_type(4)));

#define NBLK    128
#define DIN     128
#define DOUT    64
#define DMODEL  (NBLK * DIN)    // 16384
#define DOUTTOT (NBLK * DOUT)   // 8192
#define ROWS_TILE 64
#define TILES_PER_WG 8
#define LDA 136                 // padded LDS stride in bf16 elems (272 B = 17*16B)

__global__ __launch_bounds__(256, 4)
void blockdiag_gemm(const float* __restrict__ x, const float* __restrict__ W,
                    const float* __restrict__ bias, float* __restrict__ out) {
  __shared__ __bf16 Alds[ROWS_TILE][LDA];   // x tile, bf16
  __shared__ __bf16 Blds[DOUT][LDA];        // Blds[col][k] = W[k][col], bf16
  __shared__ float  biasLds[DOUT];

  const int chunk = blockIdx.x;   // 0..7   (row chunk of 512 rows)
  const int n     = blockIdx.y;   // 0..127 (block index)
  const int t     = threadIdx.x;  // 0..255
  const int lane  = t & 63;
  const int w     = t >> 6;       // wave id 0..3

  // ---- stage W block (transposed) + bias, once per WG ----
  {
    const float* Wn = W + (size_t)n * (DIN * DOUT);
    const int col = t & 63;       // output col 0..63
    const int kg  = t >> 6;       // k-group 0..3, k in [kg*32, kg*32+32)
#pragma unroll
    for (int j0 = 0; j0 < 32; j0 += 4) {
      const int k0 = kg * 32 + j0;
      float f0 = Wn[(k0 + 0) * DOUT + col];
      float f1 = Wn[(k0 + 1) * DOUT + col];
      float f2 = Wn[(k0 + 2) * DOUT + col];
      float f3 = Wn[(k0 + 3) * DOUT + col];
      bf16x4 v;
      v[0] = (__bf16)f0; v[1] = (__bf16)f1; v[2] = (__bf16)f2; v[3] = (__bf16)f3;
      *(bf16x4*)&Blds[col][k0] = v;
    }
    if (t < DOUT) biasLds[t] = bias[n * DOUT + t];
  }

  const float* xbase = x   + (size_t)(chunk * (TILES_PER_WG * ROWS_TILE)) * DMODEL + n * DIN;
  float*       obase = out + (size_t)(chunk * (TILES_PER_WG * ROWS_TILE)) * DOUTTOT + n * DOUT;

  // ---- prefetch tile 0 into registers ----
  f32x4 stage[8];
#pragma unroll
  for (int i = 0; i < 8; ++i) {
    const int idx = t + i * 256;          // 0..2047
    const int r = idx >> 5, c4 = idx & 31;
    stage[i] = *(const f32x4*)&xbase[(size_t)r * DMODEL + c4 * 4];
  }

  float bv[4];
  f32x4 acc[4];

  for (int tile = 0; tile < TILES_PER_WG; ++tile) {
    __syncthreads();   // previous tile's LDS reads done
    // ---- write staged x to LDS as bf16 ----
#pragma unroll
    for (int i = 0; i < 8; ++i) {
      const int idx = t + i * 256;
      const int r = idx >> 5, c4 = idx & 31;
      bf16x4 v;
      v[0] = (__bf16)stage[i][0]; v[1] = (__bf16)stage[i][1];
      v[2] = (__bf16)stage[i][2]; v[3] = (__bf16)stage[i][3];
      *(bf16x4*)&Alds[r][c4 * 4] = v;
    }
    __syncthreads();   // tile staged

    if (tile == 0) {
#pragma unroll
      for (int ct = 0; ct < 4; ++ct) bv[ct] = biasLds[ct * 16 + (lane & 15)];
    }

    // ---- issue next tile's global loads early (latency hides under MFMA) ----
    if (tile + 1 < TILES_PER_WG) {
      const float* xt = xbase + (size_t)(tile + 1) * ROWS_TILE * DMODEL;
#pragma unroll
      for (int i = 0; i < 8; ++i) {
        const int idx = t + i * 256;
        const int r = idx >> 5, c4 = idx & 31;
        stage[i] = *(const f32x4*)&xt[(size_t)r * DMODEL + c4 * 4];
      }
    }

    // ---- compute: wave w owns rows [w*16, w*16+16), all 64 cols ----
    const int ar = w * 16 + (lane & 15);
    const int kq = (lane >> 4) * 8;
    bf16x8 afrag[4];
#pragma unroll
    for (int ks = 0; ks < 4; ++ks)
      afrag[ks] = *(const bf16x8*)&Alds[ar][ks * 32 + kq];

#pragma unroll
    for (int ct = 0; ct < 4; ++ct) acc[ct] = (f32x4){0.f, 0.f, 0.f, 0.f};

#pragma unroll
    for (int ct = 0; ct < 4; ++ct) {
      const int bc = ct * 16 + (lane & 15);
#pragma unroll
      for (int ks = 0; ks < 4; ++ks) {
        bf16x8 bfrag = *(const bf16x8*)&Blds[bc][ks * 32 + kq];
        acc[ct] = __builtin_amdgcn_mfma_f32_16x16x32_bf16(afrag[ks], bfrag, acc[ct], 0, 0, 0);
      }
    }

    // ---- epilogue: bias + fp32 store ----
    // D layout (verified m89): col = lane&15, row = (lane>>4)*4 + reg
    float* orow = obase + (size_t)tile * ROWS_TILE * DOUTTOT;
    const int r0 = w * 16 + (lane >> 4) * 4;
#pragma unroll
    for (int ct = 0; ct < 4; ++ct) {
      const int gcol = ct * 16 + (lane & 15);
#pragma unroll
      for (int i = 0; i < 4; ++i) {
        orow[(size_t)(r0 + i) * DOUTTOT + gcol] = acc[ct][i] + bv[ct];
      }
    }
  }
}

extern "C" void kernel_launch(void* const* d_in, const int* in_sizes, int n_in,
                              void* d_out, int out_size, void* d_ws, size_t ws_size,
                              hipStream_t stream) {
  const float* x  = (const float*)d_in[0];
  const float* W  = (const float*)d_in[1];
  const float* b  = (const float*)d_in[2];
  float* out      = (float*)d_out;

  dim3 grid(8, NBLK);   // (row chunks, blocks) -> 1024 WGs
  blockdiag_gemm<<<grid, 256, 0, stream>>>(x, W, b, out);
}

// Round 2
// 98.968 us; speedup vs baseline: 1.0062x; 1.0062x over previous
//
#include <hip/hip_runtime.h>
#include <hip/hip_bf16.h>

typedef __bf16 bf16x8 __attribute__((ext_vector_type(8)));
typedef __bf16 bf16x4 __attribute__((ext_vector_type(4)));
typedef float  f32x4  __attribute__((ext_vector_type(4)));

#define NBLK    128
#define DIN     128
#define DOUT    64
#define DMODEL  (NBLK * DIN)    // 16384
#define DOUTTOT (NBLK * DOUT)   // 8192
#define ROWS_PER_WG 512
#define TILES   8               // 8 iterations x 64 rows (4 waves x 16 rows)
#define LDB 136                 // padded LDS stride (272 B) -> 2-way conflict = free

__global__ __launch_bounds__(256, 4)
void blockdiag_gemm(const float* __restrict__ x, const float* __restrict__ W,
                    const float* __restrict__ bias, float* __restrict__ out) {
  __shared__ __bf16 Blds[DOUT][LDB];   // Blds[col][k] = W[k][col], bf16
  __shared__ float  biasLds[DOUT];

  const int chunk = blockIdx.x;   // 0..7   (512-row chunk)
  const int n     = blockIdx.y;   // 0..127 (diag block)
  const int t     = threadIdx.x;
  const int lane  = t & 63;
  const int w     = t >> 6;       // wave 0..3

  // ---- stage W block (transposed to [col][k]) + bias, once ----
  {
    const float* Wn = W + (size_t)n * (DIN * DOUT);
    const int col = t & 63;
    const int kg  = t >> 6;
#pragma unroll
    for (int j0 = 0; j0 < 32; j0 += 4) {
      const int k0 = kg * 32 + j0;
      bf16x4 v;
      v[0] = (__bf16)Wn[(k0 + 0) * DOUT + col];
      v[1] = (__bf16)Wn[(k0 + 1) * DOUT + col];
      v[2] = (__bf16)Wn[(k0 + 2) * DOUT + col];
      v[3] = (__bf16)Wn[(k0 + 3) * DOUT + col];
      *(bf16x4*)&Blds[col][k0] = v;
    }
    if (t < DOUT) biasLds[t] = bias[n * DOUT + t];
  }
  __syncthreads();   // the ONLY barrier — main loop is barrier-free

  const int lrow = lane & 15;     // x-row within 16 (B-operand N index)
  const int kq   = lane >> 4;     // k-quad (8 consecutive k elems)

  // this wave's x row pointer (advances 64 rows per tile)
  const float* xrow = x + (size_t)(chunk * ROWS_PER_WG + w * 16 + lrow) * DMODEL + n * DIN;
  float*       orow = out + (size_t)(chunk * ROWS_PER_WG + w * 16 + lrow) * DOUTTOT + n * DOUT;

  // bias: lane's 4 output cols are consecutive: ct*16 + kq*4 + i
  f32x4 bv[4];
#pragma unroll
  for (int ct = 0; ct < 4; ++ct)
    bv[ct] = *(const f32x4*)&biasLds[ct * 16 + kq * 4];

  // ---- prefetch tile 0: per lane 8 floats per ks (two dwordx4) ----
  f32x4 stage[4][2];
#pragma unroll
  for (int ks = 0; ks < 4; ++ks) {
    const float* p = xrow + ks * 32 + kq * 8;
    stage[ks][0] = *(const f32x4*)p;
    stage[ks][1] = *(const f32x4*)(p + 4);
  }

  for (int tile = 0; tile < TILES; ++tile) {
    // ---- convert staged fp32 -> bf16 B-fragments (waits on this tile's loads) ----
    bf16x8 xfrag[4];
#pragma unroll
    for (int ks = 0; ks < 4; ++ks) {
      bf16x8 v;
#pragma unroll
      for (int j = 0; j < 4; ++j) {
        v[j]     = (__bf16)stage[ks][0][j];
        v[4 + j] = (__bf16)stage[ks][1][j];
      }
      xfrag[ks] = v;
    }

    // ---- issue next tile's loads immediately (fly under MFMA + store) ----
    if (tile + 1 < TILES) {
      const float* p = xrow + (size_t)(tile + 1) * 64 * DMODEL + kq * 8;
#pragma unroll
      for (int ks = 0; ks < 4; ++ks) {
        stage[ks][0] = *(const f32x4*)(p + ks * 32);
        stage[ks][1] = *(const f32x4*)(p + ks * 32 + 4);
      }
    }

    // ---- swapped MFMA: D = W^T-frag x X-frag => lane holds 4 consecutive out cols ----
    f32x4 acc[4];
#pragma unroll
    for (int ct = 0; ct < 4; ++ct) {
      acc[ct] = (f32x4){0.f, 0.f, 0.f, 0.f};
#pragma unroll
      for (int ks = 0; ks < 4; ++ks) {
        bf16x8 wfrag = *(const bf16x8*)&Blds[ct * 16 + lrow][ks * 32 + kq * 8];
        acc[ct] = __builtin_amdgcn_mfma_f32_16x16x32_bf16(wfrag, xfrag[ks], acc[ct], 0, 0, 0);
      }
    }

    // ---- epilogue: bias + one dwordx4 store per ct ----
    // D layout: "col"(lane&15) = x-row, "row"((lane>>4)*4+reg) = out col ct*16+kq*4+reg
    float* o = orow + (size_t)tile * 64 * DOUTTOT;
#pragma unroll
    for (int ct = 0; ct < 4; ++ct) {
      f32x4 r = acc[ct] + bv[ct];
      *(f32x4*)&o[ct * 16 + kq * 4] = r;
    }
  }
}

extern "C" void kernel_launch(void* const* d_in, const int* in_sizes, int n_in,
                              void* d_out, int out_size, void* d_ws, size_t ws_size,
                              hipStream_t stream) {
  const float* x  = (const float*)d_in[0];
  const float* W  = (const float*)d_in[1];
  const float* b  = (const float*)d_in[2];
  float* out      = (float*)d_out;

  dim3 grid(8, NBLK);   // 1024 WGs = 4 WGs/CU, 16 waves/CU
  blockdiag_gemm<<<grid, 256, 0, stream>>>(x, W, b, out);
}

// Round 3
// 92.843 us; speedup vs baseline: 1.0726x; 1.0660x over previous
//
#include <hip/hip_runtime.h>
#include <hip/hip_bf16.h>

typedef __bf16 bf16x8 __attribute__((ext_vector_type(8)));
typedef __bf16 bf16x4 __attribute__((ext_vector_type(4)));
typedef float  f32x4  __attribute__((ext_vector_type(4)));

#define NBLK    128
#define DIN     128
#define DOUT    64
#define DMODEL  (NBLK * DIN)    // 16384
#define DOUTTOT (NBLK * DOUT)   // 8192
#define ROWS_PER_WG 512
#define TILES   8               // 8 x 64 rows (4 waves x 16 rows)
#define LDB 136                 // padded W stride (bf16 elems)
#define LDO 65                  // padded out-tile stride (f32 elems): bank = row+4k, <=4-way

__global__ __launch_bounds__(256, 4)
void blockdiag_gemm(const float* __restrict__ x, const float* __restrict__ W,
                    const float* __restrict__ bias, float* __restrict__ out) {
  __shared__ __bf16 Blds[DOUT][LDB];     // Blds[col][k] = W[k][col], bf16
  __shared__ float  biasLds[DOUT];
  __shared__ float  Otile[64 * LDO];     // 64 rows x 64 cols staging for contiguous stores

  const int chunk = blockIdx.x;   // 0..7
  const int n     = blockIdx.y;   // 0..127
  const int t     = threadIdx.x;
  const int lane  = t & 63;
  const int w     = t >> 6;

  // ---- stage W (transposed) + bias, once ----
  {
    const float* Wn = W + (size_t)n * (DIN * DOUT);
    const int col = t & 63;
    const int kg  = t >> 6;
#pragma unroll
    for (int j0 = 0; j0 < 32; j0 += 4) {
      const int k0 = kg * 32 + j0;
      bf16x4 v;
      v[0] = (__bf16)Wn[(k0 + 0) * DOUT + col];
      v[1] = (__bf16)Wn[(k0 + 1) * DOUT + col];
      v[2] = (__bf16)Wn[(k0 + 2) * DOUT + col];
      v[3] = (__bf16)Wn[(k0 + 3) * DOUT + col];
      *(bf16x4*)&Blds[col][k0] = v;
    }
    if (t < DOUT) biasLds[t] = bias[n * DOUT + t];
  }
  __syncthreads();

  const int lrow = lane & 15;     // x-row within the wave's 16-row slice
  const int kq   = lane >> 4;     // k-quad

  const float* xrow = x + (size_t)(chunk * ROWS_PER_WG + w * 16 + lrow) * DMODEL + n * DIN;
  float*       obase = out + (size_t)(chunk * ROWS_PER_WG) * DOUTTOT + n * DOUT;

  // lane's 4 output cols (ct*16 + kq*4 + i) for bias fold
  f32x4 bv[4];
#pragma unroll
  for (int ct = 0; ct < 4; ++ct)
    bv[ct] = *(const f32x4*)&biasLds[ct * 16 + kq * 4];

  // ---- prefetch tile 0 ----
  f32x4 stage[4][2];
#pragma unroll
  for (int ks = 0; ks < 4; ++ks) {
    const float* p = xrow + ks * 32 + kq * 8;
    stage[ks][0] = *(const f32x4*)p;
    stage[ks][1] = *(const f32x4*)(p + 4);
  }

  for (int tile = 0; tile < TILES; ++tile) {
    // ---- fp32 -> bf16 fragments (waits on this tile's loads only) ----
    bf16x8 xfrag[4];
#pragma unroll
    for (int ks = 0; ks < 4; ++ks) {
      bf16x8 v;
#pragma unroll
      for (int j = 0; j < 4; ++j) {
        v[j]     = (__bf16)stage[ks][0][j];
        v[4 + j] = (__bf16)stage[ks][1][j];
      }
      xfrag[ks] = v;
    }

    // ---- issue next tile's loads (fly under MFMA + epilogue) ----
    if (tile + 1 < TILES) {
      const float* p = xrow + (size_t)(tile + 1) * 64 * DMODEL + kq * 8;
#pragma unroll
      for (int ks = 0; ks < 4; ++ks) {
        stage[ks][0] = *(const f32x4*)(p + ks * 32);
        stage[ks][1] = *(const f32x4*)(p + ks * 32 + 4);
      }
    }

    // ---- swapped MFMA: lane holds 4 consecutive out cols for row lrow ----
    f32x4 acc[4];
#pragma unroll
    for (int ct = 0; ct < 4; ++ct) {
      acc[ct] = (f32x4){0.f, 0.f, 0.f, 0.f};
#pragma unroll
      for (int ks = 0; ks < 4; ++ks) {
        bf16x8 wfrag = *(const bf16x8*)&Blds[ct * 16 + lrow][ks * 32 + kq * 8];
        acc[ct] = __builtin_amdgcn_mfma_f32_16x16x32_bf16(wfrag, xfrag[ks], acc[ct], 0, 0, 0);
      }
    }

    // ---- epilogue: acc -> LDS -> full-line contiguous global stores ----
    __syncthreads();   // previous tile's Otile reads complete
    {
      const int row = w * 16 + lrow;
#pragma unroll
      for (int ct = 0; ct < 4; ++ct) {
        f32x4 r = acc[ct] + bv[ct];
        *(f32x4*)&Otile[row * LDO + ct * 16 + kq * 4] = r;
      }
    }
    __syncthreads();   // tile fully staged
    {
      float* o = obase + (size_t)tile * 64 * DOUTTOT;
#pragma unroll
      for (int j = 0; j < 4; ++j) {
        const int idx = t + j * 256;      // 0..1023
        const int row = idx >> 4;         // 0..63
        const int c16 = idx & 15;         // 16B unit within the 256B row segment
        f32x4 v = *(const f32x4*)&Otile[row * LDO + c16 * 4];
        *(f32x4*)&o[(size_t)row * DOUTTOT + c16 * 4] = v;
      }
    }
  }
}

extern "C" void kernel_launch(void* const* d_in, const int* in_sizes, int n_in,
                              void* d_out, int out_size, void* d_ws, size_t ws_size,
                              hipStream_t stream) {
  const float* x  = (const float*)d_in[0];
  const float* W  = (const float*)d_in[1];
  const float* b  = (const float*)d_in[2];
  float* out      = (float*)d_out;

  dim3 grid(8, NBLK);   // 1024 WGs = 4 WGs/CU
  blockdiag_gemm<<<grid, 256, 0, stream>>>(x, W, b, out);
}

// Round 4
// 66.142 us; speedup vs baseline: 1.5056x; 1.4037x over previous
//
#include <hip/hip_runtime.h>
#include <hip/hip_bf16.h>

typedef __bf16 bf16x8 __attribute__((ext_vector_type(8)));
typedef __bf16 bf16x4 __attribute__((ext_vector_type(4)));
typedef float  f32x4  __attribute__((ext_vector_type(4)));

#define NBLK    128
#define DIN     128
#define DOUT    64
#define DMODEL  (NBLK * DIN)    // 16384
#define DOUTTOT (NBLK * DOUT)   // 8192
#define ROWS_PER_WG 512
#define TILES   8               // 8 x 64 rows (4 waves x 16 rows)
#define LDB 136                 // padded W stride (bf16 elems)
#define LDO 65                  // padded out-tile stride (f32 elems)

__global__ __launch_bounds__(256, 4)
void blockdiag_gemm(const float* __restrict__ x, const float* __restrict__ W,
                    const float* __restrict__ bias, float* __restrict__ out) {
  __shared__ __bf16 Blds[DOUT][LDB];     // Blds[col][k] = W[k][col], bf16
  __shared__ float  biasLds[DOUT];
  __shared__ float  Otile[64 * LDO];     // 64x64 out staging for full-line stores

  // GRID SWAP: bx = block n (fastest), by = row chunk.
  // wgid = n + chunk*128  =>  wgid % 8 == n % 8: all 8 chunk-WGs sharing W[n]
  // land on the SAME XCD (one L2 copy); consecutive WGs on an XCD read
  // adjacent 512B column segments of the same rows (contiguous XCD footprint).
  const int n     = blockIdx.x;   // 0..127
  const int chunk = blockIdx.y;   // 0..7
  const int t     = threadIdx.x;
  const int lane  = t & 63;
  const int w     = t >> 6;

  // ---- stage W (transposed) + bias, once ----
  {
    const float* Wn = W + (size_t)n * (DIN * DOUT);
    const int col = t & 63;
    const int kg  = t >> 6;
#pragma unroll
    for (int j0 = 0; j0 < 32; j0 += 4) {
      const int k0 = kg * 32 + j0;
      bf16x4 v;
      v[0] = (__bf16)Wn[(k0 + 0) * DOUT + col];
      v[1] = (__bf16)Wn[(k0 + 1) * DOUT + col];
      v[2] = (__bf16)Wn[(k0 + 2) * DOUT + col];
      v[3] = (__bf16)Wn[(k0 + 3) * DOUT + col];
      *(bf16x4*)&Blds[col][k0] = v;
    }
    if (t < DOUT) biasLds[t] = bias[n * DOUT + t];
  }
  __syncthreads();

  const int lrow = lane & 15;     // x-row within the wave's 16-row slice
  const int kq   = lane >> 4;     // k-quad

  const float* xrow  = x + (size_t)(chunk * ROWS_PER_WG + w * 16 + lrow) * DMODEL + n * DIN;
  float*       obase = out + (size_t)(chunk * ROWS_PER_WG) * DOUTTOT + n * DOUT;

  // lane's 4 output cols (ct*16 + kq*4 + i)
  f32x4 bv[4];
#pragma unroll
  for (int ct = 0; ct < 4; ++ct)
    bv[ct] = *(const f32x4*)&biasLds[ct * 16 + kq * 4];

  // ---- prefetch tile 0 ----
  f32x4 stage[4][2];
#pragma unroll
  for (int ks = 0; ks < 4; ++ks) {
    const float* p = xrow + ks * 32 + kq * 8;
    stage[ks][0] = *(const f32x4*)p;
    stage[ks][1] = *(const f32x4*)(p + 4);
  }

  for (int tile = 0; tile < TILES; ++tile) {
    // ---- fp32 -> bf16 fragments ----
    bf16x8 xfrag[4];
#pragma unroll
    for (int ks = 0; ks < 4; ++ks) {
      bf16x8 v;
#pragma unroll
      for (int j = 0; j < 4; ++j) {
        v[j]     = (__bf16)stage[ks][0][j];
        v[4 + j] = (__bf16)stage[ks][1][j];
      }
      xfrag[ks] = v;
    }

    // ---- issue next tile's loads (fly under MFMA + epilogue) ----
    if (tile + 1 < TILES) {
      const float* p = xrow + (size_t)(tile + 1) * 64 * DMODEL + kq * 8;
#pragma unroll
      for (int ks = 0; ks < 4; ++ks) {
        stage[ks][0] = *(const f32x4*)(p + ks * 32);
        stage[ks][1] = *(const f32x4*)(p + ks * 32 + 4);
      }
    }

    // ---- swapped MFMA: lane holds 4 consecutive out cols for row lrow ----
    f32x4 acc[4];
#pragma unroll
    for (int ct = 0; ct < 4; ++ct) {
      acc[ct] = (f32x4){0.f, 0.f, 0.f, 0.f};
#pragma unroll
      for (int ks = 0; ks < 4; ++ks) {
        bf16x8 wfrag = *(const bf16x8*)&Blds[ct * 16 + lrow][ks * 32 + kq * 8];
        acc[ct] = __builtin_amdgcn_mfma_f32_16x16x32_bf16(wfrag, xfrag[ks], acc[ct], 0, 0, 0);
      }
    }

    // ---- epilogue: acc -> LDS -> full-line NONTEMPORAL global stores ----
    __syncthreads();   // previous tile's Otile reads complete
    {
      const int row = w * 16 + lrow;
#pragma unroll
      for (int ct = 0; ct < 4; ++ct) {
        f32x4 r = acc[ct] + bv[ct];
        *(f32x4*)&Otile[row * LDO + ct * 16 + kq * 4] = r;
      }
    }
    __syncthreads();   // tile fully staged
    {
      float* o = obase + (size_t)tile * 64 * DOUTTOT;
#pragma unroll
      for (int j = 0; j < 4; ++j) {
        const int idx = t + j * 256;      // 0..1023
        const int row = idx >> 4;         // 0..63
        const int c16 = idx & 15;         // 16B unit within the 256B row segment
        f32x4 v = *(const f32x4*)&Otile[row * LDO + c16 * 4];
        // streamed-once output: no-allocate (nt) keeps LLC for the x stream
        __builtin_nontemporal_store(v, (f32x4*)&o[(size_t)row * DOUTTOT + c16 * 4]);
      }
    }
  }
}

extern "C" void kernel_launch(void* const* d_in, const int* in_sizes, int n_in,
                              void* d_out, int out_size, void* d_ws, size_t ws_size,
                              hipStream_t stream) {
  const float* x  = (const float*)d_in[0];
  const float* W  = (const float*)d_in[1];
  const float* b  = (const float*)d_in[2];
  float* out      = (float*)d_out;

  dim3 grid(NBLK, 8);   // bx = n (fastest) -> W-sharers co-XCD, contiguous XCD footprint
  blockdiag_gemm<<<grid, 256, 0, stream>>>(x, W, b, out);
}